// Round 12
// baseline (152.895 us; speedup 1.0000x reference)
//
#include <hip/hip_runtime.h>
#include <math.h>

// HumanPoseModule: (BT,10,6) + (BT,6,6) f32 -> (BT,24,3) f32 axis-angle.
//
// R17: PACKED f32x2 — TWO ELEMENTS PER LANE, FUSED AT THE TYPE LEVEL.
// Model (R6-R16): per-wave dependency-chain-latency-bound. ~5 waves/SIMD,
// each a serial chain load->rot6d(2 rsq)->shfl->compose->aa; VALU issue
// ~21us (VALUBusy x dur, stable across 6 kernels), exposure ~27us
// insensitive to memory coalescing (R10/R14/R15 2x2 matrix), occupancy
// (R12), wave count (R8/R9), shfl count (R16: 9->4 shfls REGRESSED
// because the chain lengthened - chain shape is what matters).
// The compiler serialized two scalar chains 3x (R8/R11 VGPR stuck ~32).
// R17 makes the two chains inseparable: elements (2g,2g+1) computed
// component-wise in ext_vector_type(2) floats - one SSA value holds both,
// so the scheduler cannot split them, and gfx90a+ has v_pk_fma_f32 /
// v_pk_mul_f32 / v_pk_add_f32 so the fma-heavy parts can issue 2-per-instr.
// Transcendentals + argmax/atan tail have no packed form -> scalar per
// component (same as two elements done separately; no loss). Loads for
// both elements issue together (MLP x2). Shfl via double bitcast.
// MARKERS: VGPR >= ~48 (pairing materialized); dur 47.5 -> ~38-43.
// FALSIFIER (pre-committed): dur >= 46 -> all levers exhausted, finalize.
//
// Identity (R7): full[j] = root @ X_j, root orthonormal =>
// local[j] = X_parent^T @ X_j; joints 1,2,3: local = X_j; joint 0: root.
//
// Lane tables (byte-packed u64s; lane l = tid&15):
//   joints: {0,1,2,3,4,5,6,9,12,13,14,15,16,17,18,19}
//   srcj:   sel<<4|row  (sel 0 = glb row, 1 = ori row)
//   pl:     parent's lane within the 16-group (lanes 0-3 unused: direct)
// Ignored joints {7,8,10,11,20,21,22,23} -> zeros, lanes 0-7, both elems.

typedef float f2 __attribute__((ext_vector_type(2)));

__device__ __forceinline__ f2 rsq2(f2 v) {
    f2 r;
    r.x = __builtin_amdgcn_rsqf(v.x);
    r.y = __builtin_amdgcn_rsqf(v.y);
    return r;
}

// scalar axis-angle tail (validated back half of mat2aa).
// t0..t3 are the RAW candidate sums (sum == 4 > 0, so the max is >= 1:
// argmax over raw == argmax over fmax(.,0), and bt needs no clamp).
__device__ __forceinline__ void aa_tail(float t0, float t1, float t2, float t3,
                                        float s1, float s2, float s3,
                                        float p1, float p2, float p3,
                                        float* __restrict__ outp) {
    int idx = 0;
    float bt = t0;
    if (t1 > bt) { bt = t1; idx = 1; }
    if (t2 > bt) { bt = t2; idx = 2; }
    if (t3 > bt) { bt = t3; idx = 3; }
    float best = __builtin_amdgcn_sqrtf(bt);  // >= 1 always
    float w = (idx == 0) ? bt : (idx == 1) ? s1 : (idx == 2) ? s2 : s3;
    float x = (idx == 0) ? s1 : (idx == 1) ? bt : (idx == 2) ? p1 : p2;
    float y = (idx == 0) ? s2 : (idx == 1) ? p1 : (idx == 2) ? bt : p3;
    float z = (idx == 0) ? s3 : (idx == 1) ? p2 : (idx == 2) ? p3 : bt;
    float inv = 0.5f * __builtin_amdgcn_rcpf(fmaxf(best, 0.1f));
    w *= inv; x *= inv; y *= inv; z *= inv;
    // unit quaternion: sin(half) == |v|, cos(half) == w
    float n = __builtin_amdgcn_sqrtf(x * x + y * y + z * z);
    // atan2_pos(n, w): minimax atan poly on [0,1], err ~2e-8
    float ax = fabsf(w);
    float mx = fmaxf(n, ax);
    float mn = fminf(n, ax);
    float a = mn * __builtin_amdgcn_rcpf(mx);
    float s = a * a;
    float p = -0.0040540580f;
    p = fmaf(p, s, 0.0218612288f);
    p = fmaf(p, s, -0.0559098861f);
    p = fmaf(p, s, 0.0964200441f);
    p = fmaf(p, s, -0.1390853351f);
    p = fmaf(p, s, 0.1994653599f);
    p = fmaf(p, s, -0.3332985605f);
    p = fmaf(p, s, 0.9999993329f);
    float r = p * a;
    r = (n > ax) ? (1.5707963268f - r) : r;
    r = (w < 0.f) ? (3.1415926536f - r) : r;
    float angle = 2.f * r;
    // angle < 1e-6 => ref's (0.5 - angle^2/48) rounds to 0.5 => inv_sh = 2
    float inv_sh = (angle < 1e-6f) ? 2.f : angle * __builtin_amdgcn_rcpf(n);
    outp[0] = x * inv_sh;
    outp[1] = y * inv_sh;
    outp[2] = z * inv_sh;
}

#define SHF2(v) __builtin_bit_cast(f2, __shfl(__builtin_bit_cast(double, (v)), pl, 16))

__global__ __launch_bounds__(256) void pose_kernel(const float* __restrict__ glb,
                                                   const float* __restrict__ ori,
                                                   float* __restrict__ out, int BT) {
    int tid = blockIdx.x * 256 + threadIdx.x;
    int pr = tid >> 4;
    int e0 = pr << 1;
    if (e0 >= BT) return;
    int l = tid & 15;
    int e1 = e0 + 1;
    bool live1 = e1 < BT;
    int e1c = live1 ? e1 : e0;   // clamp loads; stores guarded

    // byte-packed per-lane tables
    const unsigned long long OUT3_LO = 0x1B120F0C09060300ULL;  // joint*3, lanes 0-7
    const unsigned long long OUT3_HI = 0x393633302D2A2724ULL;  // lanes 8-15
    const unsigned long long SRCJ_LO = 0x0403121102010010ULL;
    const unsigned long long SRCJ_HI = 0x1514090813070605ULL;
    const unsigned long long PL_LO   = 0x0603020100000000ULL;  // parent lane, lanes 4-7
    const unsigned long long PL_HI   = 0x0D0C0A0908070707ULL;  // lanes 8-15
    const unsigned long long IGN3    = 0x45423F3C211E1815ULL;  // ignored joint*3, lanes 0-7

    int sh = (l & 7) * 8;
    int out3 = (int)(((l < 8 ? OUT3_LO : OUT3_HI) >> sh) & 0xFF);
    int srcj = (int)(((l < 8 ? SRCJ_LO : SRCJ_HI) >> sh) & 0xFF);
    int pl   = (int)(((l < 8 ? PL_LO   : PL_HI)   >> sh) & 0xFF);

    int row6 = (srcj & 15) * 6;
    bool from_ori = (srcj & 0x10) != 0;

    // both elements' loads issued together (6x dwordx2) — MLP x2
    const float* sa = from_ori ? (ori + (size_t)e0 * 36 + row6)
                               : (glb + (size_t)e0 * 60 + row6);
    const float* sb = from_ori ? (ori + (size_t)e1c * 36 + row6)
                               : (glb + (size_t)e1c * 60 + row6);
    const float2* A2 = (const float2*)sa;   // rows are 24B -> 8B aligned
    const float2* B2 = (const float2*)sb;
    float2 a0 = A2[0], a1 = A2[1], a2 = A2[2];
    float2 b0 = B2[0], b1 = B2[1], b2 = B2[2];

    // pack: d[k] = {e0's k-th input, e1's k-th input}
    f2 d0 = {a0.x, b0.x}, d1 = {a0.y, b0.y}, d2 = {a1.x, b1.x};
    f2 d3 = {a1.y, b1.y}, d4 = {a2.x, b2.x}, d5 = {a2.y, b2.y};

    // rot6d, packed (same fp sequence per component as validated rot6d_v)
    f2 r1 = rsq2(d0 * d0 + d1 * d1 + d2 * d2);
    f2 X00 = d0 * r1, X01 = d1 * r1, X02 = d2 * r1;
    f2 dt = X00 * d3 + X01 * d4 + X02 * d5;
    f2 c0 = d3 - dt * X00, c1 = d4 - dt * X01, c2 = d5 - dt * X02;
    f2 r2 = rsq2(c0 * c0 + c1 * c1 + c2 * c2);
    f2 X10 = c0 * r2, X11 = c1 * r2, X12 = c2 * r2;
    f2 X20 = X01 * X12 - X02 * X11;
    f2 X21 = X02 * X10 - X00 * X12;
    f2 X22 = X00 * X11 - X01 * X10;

    // parent's X: 9 double-shfls (2 bpermutes each = 9/element, as R7)
    f2 P00 = SHF2(X00), P01 = SHF2(X01), P02 = SHF2(X02);
    f2 P10 = SHF2(X10), P11 = SHF2(X11), P12 = SHF2(X12);
    f2 P20 = SHF2(X20), P21 = SHF2(X21), P22 = SHF2(X22);

    // L = P^T @ X (L_ij = sum_k P_ki * X_kj), packed
    f2 L00 = P00 * X00 + P10 * X10 + P20 * X20;
    f2 L01 = P00 * X01 + P10 * X11 + P20 * X21;
    f2 L02 = P00 * X02 + P10 * X12 + P20 * X22;
    f2 L10 = P01 * X00 + P11 * X10 + P21 * X20;
    f2 L11 = P01 * X01 + P11 * X11 + P21 * X21;
    f2 L12 = P01 * X02 + P11 * X12 + P21 * X22;
    f2 L20 = P02 * X00 + P12 * X10 + P22 * X20;
    f2 L21 = P02 * X01 + P12 * X11 + P22 * X21;
    f2 L22 = P02 * X02 + P12 * X12 + P22 * X22;

    // lanes 0-3: local = X (parent is root / joint 0 is root). Uniform per
    // lane across both components -> scalar-bool select on vectors.
    bool direct = (l < 4);
    L00 = direct ? X00 : L00; L01 = direct ? X01 : L01; L02 = direct ? X02 : L02;
    L10 = direct ? X10 : L10; L11 = direct ? X11 : L11; L12 = direct ? X12 : L12;
    L20 = direct ? X20 : L20; L21 = direct ? X21 : L21; L22 = direct ? X22 : L22;

    // quaternion-candidate sums, packed (argmax/select tail is scalar)
    f2 t0 = 1.f + L00 + L11 + L22;
    f2 t1 = 1.f + L00 - L11 - L22;
    f2 t2 = 1.f - L00 + L11 - L22;
    f2 t3 = 1.f - L00 - L11 + L22;
    f2 fs1 = L21 - L12, fs2 = L02 - L20, fs3 = L10 - L01;
    f2 fp1 = L10 + L01, fp2 = L02 + L20, fp3 = L12 + L21;

    // scalar tails + stores (two independent short chains)
    float* oute0 = out + (size_t)e0 * 72;
    float* oute1 = out + (size_t)e1 * 72;
    aa_tail(t0.x, t1.x, t2.x, t3.x, fs1.x, fs2.x, fs3.x, fp1.x, fp2.x, fp3.x,
            oute0 + out3);
    if (live1)
        aa_tail(t0.y, t1.y, t2.y, t3.y, fs1.y, fs2.y, fs3.y, fp1.y, fp2.y, fp3.y,
                oute1 + out3);

    // ignored joints -> exact zeros (lanes 0-7, one each, both elements)
    if (l < 8) {
        int z = (int)((IGN3 >> sh) & 0xFF);
        float* zp0 = oute0 + z;
        zp0[0] = 0.f; zp0[1] = 0.f; zp0[2] = 0.f;
        if (live1) {
            float* zp1 = oute1 + z;
            zp1[0] = 0.f; zp1[1] = 0.f; zp1[2] = 0.f;
        }
    }
}

extern "C" void kernel_launch(void* const* d_in, const int* in_sizes, int n_in,
                              void* d_out, int out_size, void* d_ws, size_t ws_size,
                              hipStream_t stream) {
    const float* glb = (const float*)d_in[0];   // (BT,10,6) f32
    const float* ori = (const float*)d_in[1];   // (BT,6,6)  f32
    float* out = (float*)d_out;                 // (BT,24,3) f32
    int BT = in_sizes[0] / 60;
    long long pairs = ((long long)BT + 1) / 2;
    long long threads = pairs * 16;
    int block = 256;
    int grid = (int)((threads + block - 1) / block);
    pose_kernel<<<grid, block, 0, stream>>>(glb, ori, out, BT);
}

// Round 14
// 150.745 us; speedup vs baseline: 1.0143x; 1.0143x over previous
//
#include <hip/hip_runtime.h>
#include <math.h>

// HumanPoseModule: (BT,10,6) + (BT,6,6) f32 -> (BT,24,3) f32 axis-angle.
//
// FINAL (R19 = R18 = R7, the session's measured-best kernel: 47.3-47.8us
// best dispatches, bench 151.1us; R18's bench was an infra failure —
// container acquisition — kernel never ran; resubmitted unchanged).
//
// Session conclusion (R6-R17): the kernel sits at a STRUCTURAL floor of
// ~47.5us/dispatch, not a counter roofline. Exhaustively measured-null:
//  - memory pattern: full 2x2 {scattered,coalesced}x{reads,writes} incl.
//    LDS-staged inputs and full-sector NT outputs -> 47.5-49.4us all cells
//    (FETCH pinned 49.2MB, WRITE 73.7MB, HBM ~31% of peak).
//  - occupancy 48-68%, block 256/1024, grid 2K-16K -> null.
//  - in-thread ILP: phased loads, __launch_bounds__(256,4), statement
//    interleave, ext_vector f32x2 packing -> backend serialized all four
//    (VGPR pinned 16-36; packed variant VALUBusy FELL to 29%).
//  - persistent grid + sched_barrier prefetch pipeline -> regressed (57us).
//  - algebraic rewrites: root-cancellation (kept), quaternion-space
//    composition (shfl 9->4 but longer serial chain -> 51.5us, reverted).
// Residual decomposition: ~21us VALU-issue (VALUBusy x dur, invariant
// across 3 algebraic forms) + ~26us per-wave dependency-chain exposure
// (load ~900cy -> rot6d 2x rsq -> 9 shfl lgkm -> matTmul -> mat2aa
// sqrt/rcp/atan chain) that wave-slot-capped ~5 waves/SIMD cannot hide
// and the compiler will not overlap within a wave.
//
// Identity: full[j] = root @ X_j with X_j = rot6d(src row j), X_0 = I;
// root orthonormal => local[j] = X_parent^T @ X_j (root cancels); joints
// 1,2,3: local = X_j; joint 0: local = root. Each lane: ONE rot6d, pull
// parent's X via 9 width-16 shfls, one 3x3 A^T B, one mat->axis-angle.
//
// Lane tables (byte-packed u64s; lane l = tid&15):
//   joints: {0,1,2,3,4,5,6,9,12,13,14,15,16,17,18,19}
//   srcj:   sel<<4|row  (sel 0 = glb row, 1 = ori row)
//   pl:     parent's lane within the 16-group (lanes 0-3 unused: direct)
// Ignored joints {7,8,10,11,20,21,22,23} -> zeros, written by lanes 0-7.

__device__ __forceinline__ void rot6d_v(float2 u0, float2 u1, float2 u2, float M[3][3]) {
    float a1x = u0.x, a1y = u0.y, a1z = u1.x;
    float a2x = u1.y, a2y = u2.x, a2z = u2.y;
    float r1 = __builtin_amdgcn_rsqf(a1x * a1x + a1y * a1y + a1z * a1z);
    float b1x = a1x * r1, b1y = a1y * r1, b1z = a1z * r1;
    float dt = b1x * a2x + b1y * a2y + b1z * a2z;
    float c2x = a2x - dt * b1x, c2y = a2y - dt * b1y, c2z = a2z - dt * b1z;
    float r2 = __builtin_amdgcn_rsqf(c2x * c2x + c2y * c2y + c2z * c2z);
    float b2x = c2x * r2, b2y = c2y * r2, b2z = c2z * r2;
    float b3x = b1y * b2z - b1z * b2y;
    float b3y = b1z * b2x - b1x * b2z;
    float b3z = b1x * b2y - b1y * b2x;
    M[0][0] = b1x; M[0][1] = b1y; M[0][2] = b1z;
    M[1][0] = b2x; M[1][1] = b2y; M[1][2] = b2z;
    M[2][0] = b3x; M[2][1] = b3y; M[2][2] = b3z;
}

// C = A^T @ B
__device__ __forceinline__ void matTmul(const float A[3][3], const float B[3][3], float C[3][3]) {
#pragma unroll
    for (int i = 0; i < 3; ++i)
#pragma unroll
        for (int j = 0; j < 3; ++j)
            C[i][j] = A[0][i] * B[0][j] + A[1][i] * B[1][j] + A[2][i] * B[2][j];
}

// atan2(y,x) for y >= 0, result in [0, pi]. Minimax atan poly on [0,1], err ~2e-8.
__device__ __forceinline__ float atan2_pos(float y, float x) {
    float ax = fabsf(x);
    float mx = fmaxf(y, ax);
    float mn = fminf(y, ax);
    float a = mn * __builtin_amdgcn_rcpf(mx);
    float s = a * a;
    float p = -0.0040540580f;
    p = fmaf(p, s, 0.0218612288f);
    p = fmaf(p, s, -0.0559098861f);
    p = fmaf(p, s, 0.0964200441f);
    p = fmaf(p, s, -0.1390853351f);
    p = fmaf(p, s, 0.1994653599f);
    p = fmaf(p, s, -0.3332985605f);
    p = fmaf(p, s, 0.9999993329f);
    float r = p * a;
    r = (y > ax) ? (1.5707963268f - r) : r;
    r = (x < 0.f) ? (3.1415926536f - r) : r;
    return r;
}

__device__ __forceinline__ void mat2aa(const float m[3][3], float* __restrict__ outp) {
    float m00 = m[0][0], m01 = m[0][1], m02 = m[0][2];
    float m10 = m[1][0], m11 = m[1][1], m12 = m[1][2];
    float m20 = m[2][0], m21 = m[2][1], m22 = m[2][2];
    float t0 = fmaxf(1.f + m00 + m11 + m22, 0.f);
    float t1 = fmaxf(1.f + m00 - m11 - m22, 0.f);
    float t2 = fmaxf(1.f - m00 + m11 - m22, 0.f);
    float t3 = fmaxf(1.f - m00 - m11 + m22, 0.f);
    // argmax over t == argmax over sqrt(t) (monotonic, same first-max ties)
    int idx = 0;
    float bt = t0;
    if (t1 > bt) { bt = t1; idx = 1; }
    if (t2 > bt) { bt = t2; idx = 2; }
    if (t3 > bt) { bt = t3; idx = 3; }
    float best = __builtin_amdgcn_sqrtf(bt);  // >= 1 always (sum of t == 4)
    float s1 = m21 - m12, s2 = m02 - m20, s3 = m10 - m01;
    float p1 = m10 + m01, p2 = m02 + m20, p3 = m12 + m21;
    float w = (idx == 0) ? bt : (idx == 1) ? s1 : (idx == 2) ? s2 : s3;
    float x = (idx == 0) ? s1 : (idx == 1) ? bt : (idx == 2) ? p1 : p2;
    float y = (idx == 0) ? s2 : (idx == 1) ? p1 : (idx == 2) ? bt : p3;
    float z = (idx == 0) ? s3 : (idx == 1) ? p2 : (idx == 2) ? p3 : bt;
    float inv = 0.5f * __builtin_amdgcn_rcpf(fmaxf(best, 0.1f));
    w *= inv; x *= inv; y *= inv; z *= inv;
    // unit quaternion: sin(half) == |v|, cos(half) == w
    float n = __builtin_amdgcn_sqrtf(x * x + y * y + z * z);
    float half = atan2_pos(n, w);
    float angle = 2.f * half;
    // angle < 1e-6 => ref's (0.5 - angle^2/48) rounds to 0.5 => inv_sh = 2
    float inv_sh = (angle < 1e-6f) ? 2.f : angle * __builtin_amdgcn_rcpf(n);
    outp[0] = x * inv_sh;
    outp[1] = y * inv_sh;
    outp[2] = z * inv_sh;
}

__global__ __launch_bounds__(256) void pose_kernel(const float* __restrict__ glb,
                                                   const float* __restrict__ ori,
                                                   float* __restrict__ out, int BT) {
    int tid = blockIdx.x * 256 + threadIdx.x;
    int e = tid >> 4;
    if (e >= BT) return;
    int l = tid & 15;

    const float* __restrict__ ge = glb + (size_t)e * 60;
    const float* __restrict__ oe = ori + (size_t)e * 36;
    float* __restrict__ oute = out + (size_t)e * 72;

    // byte-packed per-lane tables
    const unsigned long long OUT3_LO = 0x1B120F0C09060300ULL;  // joint*3, lanes 0-7
    const unsigned long long OUT3_HI = 0x393633302D2A2724ULL;  // lanes 8-15
    const unsigned long long SRCJ_LO = 0x0403121102010010ULL;
    const unsigned long long SRCJ_HI = 0x1514090813070605ULL;
    const unsigned long long PL_LO   = 0x0603020100000000ULL;  // parent lane, lanes 4-7
    const unsigned long long PL_HI   = 0x0D0C0A0908070707ULL;  // lanes 8-15
    const unsigned long long IGN3    = 0x45423F3C211E1815ULL;  // ignored joint*3, lanes 0-7

    int sh = (l & 7) * 8;
    int out3 = (int)(((l < 8 ? OUT3_LO : OUT3_HI) >> sh) & 0xFF);
    int srcj = (int)(((l < 8 ? SRCJ_LO : SRCJ_HI) >> sh) & 0xFF);
    int pl   = (int)(((l < 8 ? PL_LO   : PL_HI)   >> sh) & 0xFF);

    // own X = rot6d(src row); lane 0's src is ori row 0 -> X = root
    const float* src = (srcj & 0x10) ? (oe + (srcj & 15) * 6) : (ge + (srcj & 15) * 6);
    const float2* s2 = (const float2*)src;   // rows are 24B -> 8B aligned
    float2 u0 = s2[0], u1 = s2[1], u2 = s2[2];

    float X[3][3];
    rot6d_v(u0, u1, u2, X);

    // parent's X from the parent's lane (wave-synchronous, 16-lane groups)
    float Xp[3][3];
    {
        const float* xf = &X[0][0];
        float* pf = &Xp[0][0];
#pragma unroll
        for (int k = 0; k < 9; ++k) pf[k] = __shfl(xf[k], pl, 16);
    }

    // local = Xp^T @ X; lanes 0-3: local = X (parent is root / joint 0 is root)
    float L[3][3];
    matTmul(Xp, X, L);
#pragma unroll
    for (int i = 0; i < 3; ++i)
#pragma unroll
        for (int j = 0; j < 3; ++j)
            L[i][j] = (l < 4) ? X[i][j] : L[i][j];

    mat2aa(L, oute + out3);

    // ignored joints -> exact zeros (lanes 0-7, one each)
    if (l < 8) {
        int z = (int)((IGN3 >> sh) & 0xFF);
        float* zp = oute + z;
        zp[0] = 0.f; zp[1] = 0.f; zp[2] = 0.f;
    }
}

extern "C" void kernel_launch(void* const* d_in, const int* in_sizes, int n_in,
                              void* d_out, int out_size, void* d_ws, size_t ws_size,
                              hipStream_t stream) {
    const float* glb = (const float*)d_in[0];   // (BT,10,6) f32
    const float* ori = (const float*)d_in[1];   // (BT,6,6)  f32
    float* out = (float*)d_out;                 // (BT,24,3) f32
    int BT = in_sizes[0] / 60;
    long long threads = (long long)BT * 16;
    int block = 256;
    int grid = (int)((threads + block - 1) / block);
    pose_kernel<<<grid, block, 0, stream>>>(glb, ori, out, BT);
}